// Round 17
// baseline (188.133 us; speedup 1.0000x reference)
//
#include <hip/hip_runtime.h>
#include <hip/hip_bf16.h>
#include <stdint.h>

typedef unsigned short u16;
typedef __attribute__((ext_vector_type(8))) short short8;
typedef __attribute__((ext_vector_type(4))) float f32x4;
typedef __attribute__((ext_vector_type(16))) float f32x16;

// LPT table: j (0..23) -> qI | (s<<4); s: 0=lower K-half, 1=upper K-half, 2=unsplit.
// Lengths descend: 16,16,16,15,15,14,14,14,13,13,12,12,12,11,11,10,10,10,9,9,8,6,4,2
__constant__ unsigned char TJ[24] = {
  39, 15, 31, 14, 30, 38, 13, 29, 12, 28, 37, 11,
  27, 10, 26, 36,  9, 25,  8, 24, 35, 34, 33, 32 };

__device__ __forceinline__ u16 f2bf(float f){
  union { __hip_bfloat16 h; u16 u; } v; v.h = __float2bfloat16(f); return v.u;
}
__device__ __forceinline__ float bf2f(u16 h){
  union { uint32_t u; float f; } v; v.u = ((uint32_t)h) << 16;
  return v.f;
}
__device__ __forceinline__ f32x4 mfma16(short8 a, short8 b, f32x4 c){
  return __builtin_amdgcn_mfma_f32_16x16x32_bf16(a, b, c, 0, 0, 0);
}
__device__ __forceinline__ f32x16 mfma32(short8 a, short8 b, f32x16 c){
  return __builtin_amdgcn_mfma_f32_32x32x16_bf16(a, b, c, 0, 0, 0);
}
__device__ __forceinline__ void gl_lds16(const u16* g, u16* l){
  __builtin_amdgcn_global_load_lds((const __attribute__((address_space(1))) void*)g,
                                   (__attribute__((address_space(3))) void*)l, 16, 0, 0);
}
template<int N> __device__ __forceinline__ void waitvm(){
  if constexpr (N==0) asm volatile("s_waitcnt vmcnt(0)" ::: "memory");
  else if constexpr (N==2) asm volatile("s_waitcnt vmcnt(2)" ::: "memory");
  else if constexpr (N==4) asm volatile("s_waitcnt vmcnt(4)" ::: "memory");
  else if constexpr (N==8) asm volatile("s_waitcnt vmcnt(8)" ::: "memory");
  else static_assert(N==0 || N==2 || N==4 || N==8, "unsupported vmcnt");
}
__device__ __forceinline__ void phase_sep(){
  __builtin_amdgcn_sched_barrier(0);
  __builtin_amdgcn_s_barrier();
  __builtin_amdgcn_sched_barrier(0);
}
__device__ __forceinline__ uint32_t cvtpk(float lo, float hi){
  uint32_t r;
  asm("v_cvt_pk_bf16_f32 %0, %1, %2" : "=v"(r) : "v"(lo), "v"(hi));
  return r;
}

// ---------------- fused prep: x f32->bf16 convert + 4 weight transposes ----------------
__global__ __launch_bounds__(256) void prep(const float* __restrict__ x,
    const float* __restrict__ wq, const float* __restrict__ wk,
    const float* __restrict__ wv, const float* __restrict__ wo,
    u16* __restrict__ xbf, u16* __restrict__ wqkvT, u16* __restrict__ woT)
{
  __shared__ float tile[32][33];
  int bid = blockIdx.x;
  const int tid = threadIdx.x;
  if (bid < 8192){
    const int i = bid*256 + tid;
    const float4 v = ((const float4*)x)[i];
    ushort4 pk;
    pk.x = f2bf(v.x); pk.y = f2bf(v.y); pk.z = f2bf(v.z); pk.w = f2bf(v.w);
    ((ushort4*)xbf)[i] = pk;
    return;
  }
  bid -= 8192;
  const float* src; u16* dst; int C, bx, by;
  if (bid < 4096){ src = wq; dst = wqkvT; C = 2048; bx = bid & 63; by = bid >> 6; }
  else if (bid < 8192){ bid -= 4096; src = wo; dst = woT; C = 2048; bx = bid & 63; by = bid >> 6; }
  else if (bid < 9216){ bid -= 8192; src = wk; dst = wqkvT + 2048*2048; C = 512; bx = bid & 15; by = bid >> 4; }
  else { bid -= 9216; src = wv; dst = wqkvT + 2560*2048; C = 512; bx = bid & 15; by = bid >> 4; }
  const int R = 2048;
  const int tx = tid & 31, ty = tid >> 5;
  const int c0 = bx << 5, r0 = by << 5;
  #pragma unroll
  for (int i=0;i<4;i++)
    tile[ty + (i<<3)][tx] = src[(size_t)(r0 + ty + (i<<3))*C + c0 + tx];
  __syncthreads();
  #pragma unroll
  for (int i=0;i<4;i++)
    dst[(size_t)(c0 + ty + (i<<3))*R + r0 + tx] = f2bf(tile[tx][ty + (i<<3)]);
}

// ---------------- fused: K-RMSNorm (bid<4096) + V transpose (bid>=4096) ----------------
__global__ __launch_bounds__(256) void norm_vt(u16* __restrict__ qkv,
    const float* __restrict__ kw, u16* __restrict__ vT)
{
  const int tid = threadIdx.x;
  int bid = blockIdx.x;
  if (bid < 4096){
    const int lane = tid & 63;
    const int rid = bid*4 + (tid >> 6);
    const int row = rid >> 2;
    const int slot = rid & 3;
    u16* p = qkv + (size_t)row*3072 + 2048 + slot*128 + (lane<<1);
    const u16 r0 = p[0], r1 = p[1];
    const float a = bf2f(r0), c = bf2f(r1);
    float ss = a*a + c*c;
    #pragma unroll
    for (int off=1; off<64; off<<=1) ss += __shfl_xor(ss, off);
    const float sc = rsqrtf(ss*(1.0f/128.0f) + 1e-6f);
    const float w0 = kw[lane<<1], w1 = kw[(lane<<1)+1];
    p[0] = f2bf(a*sc*w0);
    p[1] = f2bf(c*sc*w1);
    return;
  }
  bid -= 4096;
  __shared__ u16 tile[32][33];
  const int tx = tid & 31, ty = tid >> 5;
  const int s0 = (bid & 63) << 5;
  const int d0 = ((bid >> 6) & 3) << 5;
  const int bk = bid >> 8; const int b = bk >> 2, kv = bk & 3;
  const u16* src = qkv + (size_t)b*2048*3072 + 2560 + kv*128;
  #pragma unroll
  for (int i=0;i<4;i++)
    tile[ty + (i<<3)][tx] = src[(size_t)(s0 + ty + (i<<3))*3072 + d0 + tx];
  __syncthreads();
  u16* dst = vT + (size_t)((b<<2)+kv)*128*2048;
  #pragma unroll
  for (int i=0;i<4;i++)
    dst[(size_t)(d0 + ty + (i<<3))*2048 + s0 + tx] = tile[tx][ty + (i<<3)];
}

// ---------------- 8-phase 256x192 bf16 GEMM for QKV (R15, full 256-block fill) ----------
__global__ __launch_bounds__(512, 2) void gemm192(const u16* __restrict__ A,
    const u16* __restrict__ BT, u16* __restrict__ Cp,
    int M, int N, int K, int ldc)
{
  constexpr int ASZ  = 128*64;         // u16 per A half
  constexpr int BSZ  = 64*64;          // u16 per B slot
  constexpr int DBUF = 2*ASZ + 3*BSZ;  // 28672 u16 = 56 KB
  __shared__ u16 lds[2*DBUF];
  const int tid = threadIdx.x;
  const int w = tid >> 6, lane = tid & 63;
  const int l15 = lane & 15, lg = lane >> 4;
  const int wm = w >> 2, wn = w & 3;
  const int nbx = N / 192;             // 16
  const int nwg = gridDim.x;
  int bid = blockIdx.x;
  bid = (bid & 7) * (nwg >> 3) + (bid >> 3);   // bijective XCD swizzle (nwg%8==0)
  const int m0 = (bid / nbx) << 8;
  const int n0 = (bid % nbx) * 192;

  const u16* gA0 = A  + (size_t)m0*K;
  const u16* gA1 = gA0 + (size_t)128*K;
  const u16* gB  = BT + (size_t)n0*K;

  auto slotA = [&](int d, int h)->u16*{ return lds + d*DBUF + h*ASZ; };
  auto slotB = [&](int d, int s)->u16*{ return lds + d*DBUF + 2*ASZ + s*BSZ; };

  auto stage128 = [&](const u16* gbase, int kt, u16* sbase){
    #pragma unroll
    for (int i=0;i<2;i++){
      const int p = (i<<9) + tid;
      const int row = p>>3, sg = (p&7) ^ (row&7);
      gl_lds16(gbase + (size_t)row*K + (kt<<6) + (sg<<3), sbase + (p<<3));
    }
  };
  auto stage64 = [&](const u16* gbase, int kt, u16* sbase){
    const int row = tid>>3, sg = (tid&7) ^ (row&7);
    gl_lds16(gbase + (size_t)row*K + (kt<<6) + (sg<<3), sbase + (tid<<3));
  };
  auto stA = [&](int kt, int d){ stage128(gA0, kt, slotA(d,0));
                                 stage128(gA1, kt, slotA(d,1)); };
  auto stB = [&](int kt, int d){ stage64(gB,               kt, slotB(d,0));
                                 stage64(gB + (size_t) 64*K, kt, slotB(d,1));
                                 stage64(gB + (size_t)128*K, kt, slotB(d,2)); };
  auto frag_at = [&](const u16* buf, int lrow, int kk)->short8{
    const int s = ((kk<<2)+lg) ^ (lrow&7);
    return *(const short8*)(buf + (((lrow<<3)+s)<<3));
  };

  short8 af[4][2], bfe[2][2], bfo[2];
  f32x4 acc[8][3];
  #pragma unroll
  for (int m=0;m<8;m++)
    #pragma unroll
    for (int n=0;n<3;n++) acc[m][n] = (f32x4){0.f,0.f,0.f,0.f};

  auto rd_a = [&](int d, int mq){
    #pragma unroll
    for (int m=0;m<4;m++)
      #pragma unroll
      for (int kk=0;kk<2;kk++)
        af[m][kk] = frag_at(slotA(d,wm), (mq<<6) + (m<<4) + l15, kk);
  };
  auto rd_be = [&](int d){                   // n-frags 0,1
    #pragma unroll
    for (int n=0;n<2;n++){
      const int r = wn*48 + (n<<4) + l15;
      #pragma unroll
      for (int kk=0;kk<2;kk++)
        bfe[n][kk] = frag_at(slotB(d, r>>6), r&63, kk);
    }
  };
  auto rd_bo = [&](int d){                   // n-frag 2
    const int r = wn*48 + 32 + l15;
    #pragma unroll
    for (int kk=0;kk<2;kk++)
      bfo[kk] = frag_at(slotB(d, r>>6), r&63, kk);
  };
  auto mf_e = [&](int mb){
    __builtin_amdgcn_s_setprio(1);
    #pragma unroll
    for (int m=0;m<4;m++)
      #pragma unroll
      for (int n=0;n<2;n++)
        #pragma unroll
        for (int kk=0;kk<2;kk++)
          acc[mb+m][n] = mfma16(af[m][kk], bfe[n][kk], acc[mb+m][n]);
    __builtin_amdgcn_s_setprio(0);
  };
  auto mf_o = [&](int mb){
    __builtin_amdgcn_s_setprio(1);
    #pragma unroll
    for (int m=0;m<4;m++)
      #pragma unroll
      for (int kk=0;kk<2;kk++)
        acc[mb+m][2] = mfma16(af[m][kk], bfo[kk], acc[mb+m][2]);
    __builtin_amdgcn_s_setprio(0);
  };

  stA(0,0); stB(0,0); stA(1,1);
  waitvm<4>();
  phase_sep();

  const int niter = K >> 7;            // two K-tiles (BK=64) per iteration
  for (int i=0; i<niter; ++i){
    const bool full = (i+1 < niter);
    const int t1 = 2*i+1;
    rd_a(0, 0); rd_be(0);
    stB(t1, 1);
    phase_sep();
    mf_e(0);
    phase_sep();
    rd_bo(0);
    phase_sep();
    mf_o(0);
    phase_sep();
    rd_a(0, 1);
    phase_sep();
    mf_o(4);
    phase_sep();
    rd_be(0);
    if (full) stA(t1+1, 0);
    phase_sep();
    mf_e(4);
    if (full) waitvm<4>(); else waitvm<0>();
    phase_sep();
    rd_a(1, 0); rd_be(1);
    if (full) stB(t1+1, 0);
    phase_sep();
    mf_e(0);
    phase_sep();
    rd_bo(1);
    phase_sep();
    mf_o(0);
    phase_sep();
    rd_a(1, 1);
    phase_sep();
    mf_o(4);
    phase_sep();
    rd_be(1);
    if (full) stA(t1+2, 1);
    phase_sep();
    mf_e(4);
    if (full) waitvm<4>();
    phase_sep();
  }

  #pragma unroll
  for (int m=0;m<8;m++){
    #pragma unroll
    for (int n=0;n<3;n++){
      const int col = n0 + wn*48 + (n<<4) + l15;
      #pragma unroll
      for (int r=0;r<4;r++){
        const int row = m0 + (wm<<7) + (m<<4) + (lg<<2) + r;
        Cp[(size_t)row*ldc + col] = f2bf(acc[m][n][r]);
      }
    }
  }
}

// ---------------- 8-phase BMx256 bf16 GEMM (out-proj; unchanged) ----------------
template<int BM, int CBF16>
__global__ __launch_bounds__(512, 2) void gemm8(const u16* __restrict__ A,
    const u16* __restrict__ BT, void* __restrict__ Cp,
    int M, int N, int K, int ldc)
{
  constexpr int MF   = BM/32;          // M-frags per wave
  constexpr int MQ   = MF/2;           // frags per quadrant phase
  constexpr int AH   = BM/2;           // rows per A half-slot
  constexpr int ASZ  = AH*64;          // u16 per A half-slot
  constexpr int DBUF = 2*ASZ + 16384;  // u16 per dbuf
  constexpr int WV   = (BM==256) ? 4 : 2;  // steady-state vmcnt
  __shared__ u16 lds[2*DBUF];
  const int tid = threadIdx.x;
  const int w = tid >> 6, lane = tid & 63;
  const int l15 = lane & 15, lg = lane >> 4;
  const int wm = w >> 2, wn = w & 3;
  const int nbx = N >> 8;
  const int nwg = gridDim.x;
  int bid = blockIdx.x;
  bid = (bid & 7) * (nwg >> 3) + (bid >> 3);   // bijective XCD swizzle (nwg%8==0)
  const int m0 = (bid / nbx) * BM;
  const int n0 = (bid % nbx) << 8;

  const u16* gA0 = A  + (size_t)m0*K;
  const u16* gA1 = gA0 + (size_t)AH*K;
  const u16* gB0 = BT + (size_t)n0*K;
  const u16* gB1 = gB0 + (size_t)128*K;

  auto slotA = [&](int d, int h)->u16*{ return lds + d*DBUF + h*ASZ; };
  auto slotB = [&](int d, int h)->u16*{ return lds + d*DBUF + 2*ASZ + h*8192; };

  auto stage_half = [&](const u16* gbase, int kt, u16* sbase, int rows){
    const int iters = rows >> 6;               // rows*8/512
    for (int i=0;i<iters;i++){
      const int p = (i<<9) + tid;
      const int row = p>>3, sg = (p&7) ^ (row&7);
      gl_lds16(gbase + (size_t)row*K + (kt<<6) + (sg<<3), sbase + (p<<3));
    }
  };
  auto stA = [&](int kt, int d){ stage_half(gA0, kt, slotA(d,0), AH);
                                 stage_half(gA1, kt, slotA(d,1), AH); };
  auto stB = [&](int kt, int d){ stage_half(gB0, kt, slotB(d,0), 128);
                                 stage_half(gB1, kt, slotB(d,1), 128); };
  auto frag_at = [&](const u16* buf, int lrow, int kk)->short8{
    const int s = ((kk<<2)+lg) ^ (lrow&7);
    return *(const short8*)(buf + (((lrow<<3)+s)<<3));
  };

  short8 af[MQ][2], bfe[2][2], bfo[2][2];
  f32x4 acc[MF][4];
  #pragma unroll
  for (int m=0;m<MF;m++)
    #pragma unroll
    for (int n=0;n<4;n++) acc[m][n] = (f32x4){0.f,0.f,0.f,0.f};

  const int bh = wn>>1;                // my B-half index
  const int brow0 = ((wn&1)<<6) + l15; // base local row in B slot

  auto rd_a = [&](const u16* buf, int mq){
    #pragma unroll
    for (int m=0;m<MQ;m++)
      #pragma unroll
      for (int kk=0;kk<2;kk++)
        af[m][kk] = frag_at(buf, mq*(BM>>2) + (m<<4) + l15, kk);
  };
  auto rd_b = [&](const u16* buf, int nq, short8 (*dst)[2]){
    #pragma unroll
    for (int n=0;n<2;n++)
      #pragma unroll
      for (int kk=0;kk<2;kk++)
        dst[n][kk] = frag_at(buf, brow0 + (nq<<5) + (n<<4), kk);
  };
  auto do_mfma = [&](int mb, int nb, short8 (*bf)[2]){
    __builtin_amdgcn_s_setprio(1);
    #pragma unroll
    for (int m=0;m<MQ;m++)
      #pragma unroll
      for (int n=0;n<2;n++)
        #pragma unroll
        for (int kk=0;kk<2;kk++)
          acc[mb+m][nb+n] = mfma16(af[m][kk], bf[n][kk], acc[mb+m][nb+n]);
    __builtin_amdgcn_s_setprio(0);
  };

  stA(0,0); stB(0,0); stA(1,1);
  waitvm<WV>();
  phase_sep();

  const int niter = K >> 7;            // two K-tiles (BK=64) per iteration
  for (int i=0; i<niter; ++i){
    const bool full = (i+1 < niter);
    const int t1 = 2*i+1;
    rd_a(slotA(0,wm), 0); rd_b(slotB(0,bh), 0, bfe);
    stB(t1, 1);
    phase_sep();
    do_mfma(0, 0, bfe);
    phase_sep();
    rd_b(slotB(0,bh), 1, bfo);
    phase_sep();
    do_mfma(0, 2, bfo);
    phase_sep();
    rd_a(slotA(0,wm), 1);
    phase_sep();
    do_mfma(MQ, 2, bfo);
    phase_sep();
    rd_b(slotB(0,bh), 0, bfe);
    if (full) stA(t1+1, 0);
    phase_sep();
    do_mfma(MQ, 0, bfe);
    if (full) waitvm<WV>(); else waitvm<0>();
    phase_sep();
    rd_a(slotA(1,wm), 0); rd_b(slotB(1,bh), 0, bfe);
    if (full) stB(t1+1, 0);
    phase_sep();
    do_mfma(0, 0, bfe);
    phase_sep();
    rd_b(slotB(1,bh), 1, bfo);
    phase_sep();
    do_mfma(0, 2, bfo);
    phase_sep();
    rd_a(slotA(1,wm), 1);
    phase_sep();
    do_mfma(MQ, 2, bfo);
    phase_sep();
    rd_b(slotB(1,bh), 0, bfe);
    if (full) stA(t1+2, 1);
    phase_sep();
    do_mfma(MQ, 0, bfe);
    if (full) waitvm<WV>();
    phase_sep();
  }

  #pragma unroll
  for (int m=0;m<MF;m++){
    #pragma unroll
    for (int n=0;n<4;n++){
      const int col = n0 + (wn<<6) + (n<<4) + l15;
      #pragma unroll
      for (int r=0;r<4;r++){
        const int row = m0 + wm*AH + (m<<4) + (lg<<2) + r;
        if (CBF16) ((u16*)Cp)[(size_t)row*ldc + col] = f2bf(acc[m][n][r]);
        else       ((float*)Cp)[(size_t)row*ldc + col] = acc[m][n][r];
      }
    }
  }
}

// ---------------- causal GQA flash attention: K-split flash-decode (R11 fixed) ----------
// grid 768 x 256 thr / 4 waves, 48 KB LDS, launch_bounds(256,2) -> ~130 VGPR,
// NO SPILL (R11's (256,3) forced a spill to 84 VGPR -- its real failure).
// j = bid>>5 indexes LPT table: qI<=7 whole (nt<=16); qI>=8 split into two
// K-halves (<=16 iters). Split halves write unnormalized f32 O + (m,l)
// (partials in d_out, overwritten later by out-proj); attn_combine merges.
// Per-wave math = R14 (swapped QK^T, fused Q-RMSNorm, lane-local softmax,
// defer-max, T12 in-register P).
__global__ __launch_bounds__(256, 2) void attn_kernel(const u16* __restrict__ qkv,
    const u16* __restrict__ vT, const float* __restrict__ qw,
    u16* __restrict__ aout, float* __restrict__ partial, float2* __restrict__ mlbuf)
{
  __shared__ u16 Klds[2][8192];   // [row 64][slot 16] 16B units, slot = d0 ^ (row&15)
  __shared__ u16 Vlds[8192];      // [rp=d/2][sl 16], sl = ((d&1)<<3 | k8) ^ (rp&15)
  const int tid = threadIdx.x;
  const int w = tid >> 6, lane = tid & 63;
  const int l31 = lane & 31, hi = lane >> 5;
  const int bid = blockIdx.x;
  const int j = bid >> 5;
  const int grp = bid & 31;
  const int b = grp >> 4, kvh = (grp >> 2) & 3, hh = grp & 3;
  const int h = (kvh<<2) + hh;
  const unsigned v_ = TJ[j];
  const int qI = v_ & 15, s = v_ >> 4;       // s: 0 lower, 1 upper, 2 unsplit
  const int tb = (s == 1) ? (qI + 1) : 0;
  const int te = (s == 0) ? (qI + 1) : (2*qI + 2);
  const int qb = qI*128 + (w<<5);            // this wave's 32 q-rows

  const u16* qkvb = qkv + (size_t)b*2048*3072;
  short8 qf[8];
  {
    const u16* qp = qkvb + (size_t)(qb + l31)*3072 + h*128 + hi*8;
    #pragma unroll
    for (int kk=0;kk<8;kk++) qf[kk] = *(const short8*)(qp + kk*16);
    // ---- fused Q-RMSNorm (idempotent: register-only, no writeback)
    float ss = 0.f;
    #pragma unroll
    for (int kk=0;kk<8;kk++)
      #pragma unroll
      for (int e=0;e<8;e++){
        const float v = bf2f((u16)qf[kk][e]);
        ss += v*v;
      }
    ss += __shfl_xor(ss, 32);
    const float sc = rsqrtf(ss*(1.0f/128.0f) + 1e-6f) * 0.1275187952317199f;
    #pragma unroll
    for (int kk=0;kk<8;kk++){
      #pragma unroll
      for (int e=0;e<8;e++){
        const float wv_ = qw[kk*16 + hi*8 + e];
        qf[kk][e] = (short)f2bf(bf2f((u16)qf[kk][e]) * sc * wv_);
      }
    }
  }
  f32x16 oacc[4];
  #pragma unroll
  for (int d=0;d<4;d++)
    #pragma unroll
    for (int r=0;r<16;r++) oacc[d][r] = 0.f;
  float m_run = -__builtin_inff(), lsum = 0.f;

  const u16* kb_ = qkvb + 2048 + kvh*128;
  const u16* vb_ = vT + (size_t)((b<<2)+kvh)*128*2048;

  auto stageK = [&](int t, int buf){
    #pragma unroll
    for (int i=0;i<4;i++){
      const int u = (i<<8) + tid;            // 0..1023
      const int row = u>>4, d0 = (u&15) ^ (row&15);
      gl_lds16(kb_ + (size_t)((t<<6)+row)*3072 + (d0<<3), &Klds[buf][u<<3]);
    }
  };
  auto stageV = [&](int t){
    #pragma unroll
    for (int i=0;i<4;i++){
      const int u = (i<<8) + tid;
      const int rp = u>>4, z = (u&15) ^ (rp&15);
      const int d = (rp<<1) + (z>>3), k8 = z&7;
      gl_lds16(vb_ + (size_t)d*2048 + (t<<6) + (k8<<3), &Vlds[u<<3]);
    }
  };

  stageK(tb, 0);
  int kbuf = 0;
  for (int t=tb; t<te; ++t){
    const bool pre = (t+1 < te);
    stageV(t);
    if (pre) stageK(t+1, kbuf^1);
    if (pre) waitvm<8>(); else waitvm<4>();  // K(t) landed, prefetches in flight
    phase_sep();
    const int t0 = t<<6;
    // ---- S^T = K Q
    f32x16 s0, s1;
    #pragma unroll
    for (int r=0;r<16;r++){ s0[r] = 0.f; s1[r] = 0.f; }
    __builtin_amdgcn_s_setprio(1);
    #pragma unroll
    for (int kk=0;kk<8;kk++){
      const int d0 = (kk<<1) + hi;
      const short8 k0 = *(const short8*)&Klds[kbuf][((l31<<4) + (d0 ^ (l31&15)))<<3];
      s0 = mfma32(k0, qf[kk], s0);
      const int r1 = 32 + l31;
      const short8 k1 = *(const short8*)&Klds[kbuf][((r1<<4) + (d0 ^ (r1&15)))<<3];
      s1 = mfma32(k1, qf[kk], s1);
    }
    __builtin_amdgcn_s_setprio(0);
    // ---- causal mask
    if (t0 + 63 > qb){
      const int qrel = qb + l31 - t0;
      #pragma unroll
      for (int r=0;r<16;r++){
        const int kloc = (r&3) + ((r>>2)<<3) + (hi<<2);
        if (kloc      > qrel) s0[r] = -__builtin_inff();
        if (kloc + 32 > qrel) s1[r] = -__builtin_inff();
      }
    }
    // ---- online softmax (defer-max, exp2 domain)
    float t8[8];
    #pragma unroll
    for (int i=0;i<8;i++) t8[i] = fmaxf(fmaxf(s0[i], s0[i+8]), fmaxf(s1[i], s1[i+8]));
    #pragma unroll
    for (int i=0;i<4;i++) t8[i] = fmaxf(t8[i], t8[i+4]);
    float mx = fmaxf(fmaxf(t8[0],t8[1]), fmaxf(t8[2],t8[3]));
    mx = fmaxf(mx, __shfl_xor(mx, 32));
    const bool noskip = !__all(mx - m_run <= 8.0f);
    const float mnew = noskip ? fmaxf(m_run, mx) : m_run;
    float rs = 0.f;
    #pragma unroll
    for (int i=0;i<16;i++){
      s0[i] = __builtin_amdgcn_exp2f(s0[i] - mnew);
      s1[i] = __builtin_amdgcn_exp2f(s1[i] - mnew);
      rs += s0[i] + s1[i];
    }
    rs += __shfl_xor(rs, 32);
    if (noskip){
      const float corr = __builtin_amdgcn_exp2f(m_run - mnew);
      m_run = mnew;
      lsum = lsum*corr + rs;
      #pragma unroll
      for (int r=0;r<16;r++){
        const float cr = __shfl(corr, (r&3) + ((r>>2)<<3) + (hi<<2));
        #pragma unroll
        for (int db=0;db<4;db++) oacc[db][r] *= cr;
      }
    } else {
      lsum += rs;
    }
    // ---- T12: PV A-frags in-register via cvt_pk + permlane32_swap
    uint32_t paw[4][4];
    #pragma unroll
    for (int kk=0;kk<4;kk++){
      const int base = (kk&1)<<3;
      float v0,v1,v2,v3,v4,v5,v6,v7;
      if (kk<2){ v0=s0[base+0]; v1=s0[base+1]; v2=s0[base+2]; v3=s0[base+3];
                 v4=s0[base+4]; v5=s0[base+5]; v6=s0[base+6]; v7=s0[base+7]; }
      else     { v0=s1[base+0]; v1=s1[base+1]; v2=s1[base+2]; v3=s1[base+3];
                 v4=s1[base+4]; v5=s1[base+5]; v6=s1[base+6]; v7=s1[base+7]; }
      uint32_t a0 = cvtpk(v0, v1), a1 = cvtpk(v2, v3);
      uint32_t b0 = cvtpk(v4, v5), b1 = cvtpk(v6, v7);
      asm volatile("v_permlane32_swap_b32 %0, %1" : "+v"(a0), "+v"(b0));
      asm volatile("v_permlane32_swap_b32 %0, %1" : "+v"(a1), "+v"(b1));
      paw[kk][0] = a0; paw[kk][1] = a1; paw[kk][2] = b0; paw[kk][3] = b1;
    }
    if (pre) waitvm<4>(); else waitvm<0>();  // V(t) landed, K(t+1) in flight
    phase_sep();
    // ---- O += P V
    __builtin_amdgcn_s_setprio(1);
    #pragma unroll
    for (int kk=0;kk<4;kk++){
      union { uint32_t w[4]; short8 v; } pu;
      pu.w[0]=paw[kk][0]; pu.w[1]=paw[kk][1]; pu.w[2]=paw[kk][2]; pu.w[3]=paw[kk][3];
      const short8 pa = pu.v;
      #pragma unroll
      for (int db=0;db<4;db++){
        const int d = (db<<5) + l31, rp = d>>1;
        const int sl = (((d&1)<<3) | ((kk<<1)+hi)) ^ (rp&15);
        const short8 vv = *(const short8*)&Vlds[((rp<<4)+sl)<<3];
        oacc[db] = mfma32(pa, vv, oacc[db]);
      }
    }
    __builtin_amdgcn_s_setprio(0);
    phase_sep();                             // PV reads done before next stageV
    kbuf ^= 1;
  }

  if (s == 2){
    // ---- whole tile: normalize rows, store bf16
    const float inv = 1.0f / lsum;
    #pragma unroll
    for (int r=0;r<16;r++){
      const int qr = (r&3) + ((r>>2)<<3) + (hi<<2);
      const float ivr = __shfl(inv, qr);
      u16* op = aout + (size_t)(b*2048 + qI*128 + (w<<5) + qr)*2048 + h*128 + l31;
      #pragma unroll
      for (int db=0;db<4;db++)
        op[db<<5] = f2bf(oacc[db][r] * ivr);
    }
  } else {
    // ---- split half: write unnormalized f32 O + (m,l)
    const int tau = (((b<<4) + h)<<3) + (qI - 8);      // 0..255
    float* pO = partial + (size_t)((tau<<1)+s)*16384;
    #pragma unroll
    for (int r=0;r<16;r++){
      const int qr = (r&3) + ((r>>2)<<3) + (hi<<2);
      float* pr = pO + ((w<<5)+qr)*128 + l31;
      #pragma unroll
      for (int db=0;db<4;db++) pr[db<<5] = oacc[db][r];
    }
    if (hi == 0)
      mlbuf[((tau<<1)+s)*128 + (w<<5) + l31] = make_float2(m_run, lsum);
  }
}

// ---------------- combine the two K-halves of split tiles ----------------
__global__ __launch_bounds__(256) void attn_combine(const float* __restrict__ partial,
    const float2* __restrict__ mlbuf, u16* __restrict__ aout)
{
  const int tau = blockIdx.x;
  const int b = tau >> 7, h = (tau >> 3) & 15, qI = (tau & 7) + 8;
  const int row = threadIdx.x >> 1;
  const int c0 = (threadIdx.x & 1) << 6;
  const float2 ml0 = mlbuf[(tau<<1)*128 + row];
  const float2 ml1 = mlbuf[((tau<<1)+1)*128 + row];
  const float M = fmaxf(ml0.x, ml1.x);
  float w0 = __builtin_amdgcn_exp2f(ml0.x - M);
  float w1 = __builtin_amdgcn_exp2f(ml1.x - M);
  const float inv = 1.0f / (w0*ml0.y + w1*ml1.y);
  w0 *= inv; w1 *= inv;
  const float4* P0 = (const float4*)(partial + (size_t)(tau<<1)*16384 + row*128 + c0);
  const float4* P1 = (const float4*)(partial + (size_t)((tau<<1)+1)*16384 + row*128 + c0);
  ushort4* op = (ushort4*)(aout + (size_t)(b*2048 + qI*128 + row)*2048 + h*128 + c0);
  #pragma unroll
  for (int i=0;i<16;i++){
    const float4 a = P0[i], c = P1[i];
    ushort4 o;
    o.x = f2bf(w0*a.x + w1*c.x);
    o.y = f2bf(w0*a.y + w1*c.y);
    o.z = f2bf(w0*a.z + w1*c.z);
    o.w = f2bf(w0*a.w + w1*c.w);
    op[i] = o;
  }
}

extern "C" void kernel_launch(void* const* d_in, const int* in_sizes, int n_in,
                              void* d_out, int out_size, void* d_ws, size_t ws_size,
                              hipStream_t stream) {
  const float* x  = (const float*)d_in[0];
  const float* wq = (const float*)d_in[1];
  const float* wk = (const float*)d_in[2];
  const float* wv = (const float*)d_in[3];
  const float* wo = (const float*)d_in[4];
  const float* qw = (const float*)d_in[5];
  const float* kw = (const float*)d_in[6];
  char* ws = (char*)d_ws;
  u16* xbf   = (u16*)(ws);                 // 16 MB; reused as attn_out
  u16* wqkvT = (u16*)(ws + 16777216);      // 12 MB (dead after gemm192; ml reuses)
  u16* woT   = (u16*)(ws + 29360128);      // 8 MB:  [2048][2048]
  u16* qkv   = (u16*)(ws + 37748736);      // 24 MB: [4096][3072] q|k|v
  u16* vT    = (u16*)(ws + 62914560);      // 4 MB:  [8][128][2048]
  float2* ml = (float2*)(ws + 16777216);   // 512 KB, reuses dead wqkvT region
  float* out = (float*)d_out;              // partials live here pre-out-proj

  prep<<<18432, 256, 0, stream>>>(x, wq, wk, wv, wo, xbf, wqkvT, woT);
  gemm192<<<256, 512, 0, stream>>>(xbf, wqkvT, qkv, 4096, 3072, 2048, 3072);
  norm_vt<<<6144, 256, 0, stream>>>(qkv, kw, vT);
  attn_kernel<<<768, 256, 0, stream>>>(qkv, vT, qw, xbf, out, ml);
  attn_combine<<<256, 256, 0, stream>>>(out, ml, xbf);
  gemm8<128,0><<<256, 512, 0, stream>>>(xbf, woT, out, 4096, 2048, 2048, 2048);
}

// Round 18
// 173.984 us; speedup vs baseline: 1.0813x; 1.0813x over previous
//
#include <hip/hip_runtime.h>
#include <hip/hip_bf16.h>
#include <stdint.h>

typedef unsigned short u16;
typedef __attribute__((ext_vector_type(8))) short short8;
typedef __attribute__((ext_vector_type(4))) float f32x4;
typedef __attribute__((ext_vector_type(16))) float f32x16;

__device__ __forceinline__ u16 f2bf(float f){
  union { __hip_bfloat16 h; u16 u; } v; v.h = __float2bfloat16(f); return v.u;
}
__device__ __forceinline__ float bf2f(u16 h){
  union { uint32_t u; float f; } v; v.u = ((uint32_t)h) << 16;
  return v.f;
}
__device__ __forceinline__ f32x4 mfma16(short8 a, short8 b, f32x4 c){
  return __builtin_amdgcn_mfma_f32_16x16x32_bf16(a, b, c, 0, 0, 0);
}
__device__ __forceinline__ f32x16 mfma32(short8 a, short8 b, f32x16 c){
  return __builtin_amdgcn_mfma_f32_32x32x16_bf16(a, b, c, 0, 0, 0);
}
__device__ __forceinline__ void gl_lds16(const u16* g, u16* l){
  __builtin_amdgcn_global_load_lds((const __attribute__((address_space(1))) void*)g,
                                   (__attribute__((address_space(3))) void*)l, 16, 0, 0);
}
template<int N> __device__ __forceinline__ void waitvm(){
  if constexpr (N==0) asm volatile("s_waitcnt vmcnt(0)" ::: "memory");
  else if constexpr (N==2) asm volatile("s_waitcnt vmcnt(2)" ::: "memory");
  else if constexpr (N==4) asm volatile("s_waitcnt vmcnt(4)" ::: "memory");
  else if constexpr (N==8) asm volatile("s_waitcnt vmcnt(8)" ::: "memory");
  else static_assert(N==0 || N==2 || N==4 || N==8, "unsupported vmcnt");
}
__device__ __forceinline__ void phase_sep(){
  __builtin_amdgcn_sched_barrier(0);
  __builtin_amdgcn_s_barrier();
  __builtin_amdgcn_sched_barrier(0);
}
__device__ __forceinline__ uint32_t cvtpk(float lo, float hi){
  uint32_t r;
  asm("v_cvt_pk_bf16_f32 %0, %1, %2" : "=v"(r) : "v"(lo), "v"(hi));
  return r;
}

// ---------------- fused prep: x f32->bf16 convert + 4 weight transposes ----------------
__global__ __launch_bounds__(256) void prep(const float* __restrict__ x,
    const float* __restrict__ wq, const float* __restrict__ wk,
    const float* __restrict__ wv, const float* __restrict__ wo,
    u16* __restrict__ xbf, u16* __restrict__ wqkvT, u16* __restrict__ woT)
{
  __shared__ float tile[32][33];
  int bid = blockIdx.x;
  const int tid = threadIdx.x;
  if (bid < 8192){
    const int i = bid*256 + tid;
    const float4 v = ((const float4*)x)[i];
    ushort4 pk;
    pk.x = f2bf(v.x); pk.y = f2bf(v.y); pk.z = f2bf(v.z); pk.w = f2bf(v.w);
    ((ushort4*)xbf)[i] = pk;
    return;
  }
  bid -= 8192;
  const float* src; u16* dst; int C, bx, by;
  if (bid < 4096){ src = wq; dst = wqkvT; C = 2048; bx = bid & 63; by = bid >> 6; }
  else if (bid < 8192){ bid -= 4096; src = wo; dst = woT; C = 2048; bx = bid & 63; by = bid >> 6; }
  else if (bid < 9216){ bid -= 8192; src = wk; dst = wqkvT + 2048*2048; C = 512; bx = bid & 15; by = bid >> 4; }
  else { bid -= 9216; src = wv; dst = wqkvT + 2560*2048; C = 512; bx = bid & 15; by = bid >> 4; }
  const int R = 2048;
  const int tx = tid & 31, ty = tid >> 5;
  const int c0 = bx << 5, r0 = by << 5;
  #pragma unroll
  for (int i=0;i<4;i++)
    tile[ty + (i<<3)][tx] = src[(size_t)(r0 + ty + (i<<3))*C + c0 + tx];
  __syncthreads();
  #pragma unroll
  for (int i=0;i<4;i++)
    dst[(size_t)(c0 + ty + (i<<3))*R + r0 + tx] = f2bf(tile[tx][ty + (i<<3)]);
}

// ---------------- fused: K-RMSNorm (bid<4096) + V transpose (bid>=4096) ----------------
__global__ __launch_bounds__(256) void norm_vt(u16* __restrict__ qkv,
    const float* __restrict__ kw, u16* __restrict__ vT)
{
  const int tid = threadIdx.x;
  int bid = blockIdx.x;
  if (bid < 4096){
    const int lane = tid & 63;
    const int rid = bid*4 + (tid >> 6);
    const int row = rid >> 2;
    const int slot = rid & 3;
    u16* p = qkv + (size_t)row*3072 + 2048 + slot*128 + (lane<<1);
    const u16 r0 = p[0], r1 = p[1];
    const float a = bf2f(r0), c = bf2f(r1);
    float ss = a*a + c*c;
    #pragma unroll
    for (int off=1; off<64; off<<=1) ss += __shfl_xor(ss, off);
    const float sc = rsqrtf(ss*(1.0f/128.0f) + 1e-6f);
    const float w0 = kw[lane<<1], w1 = kw[(lane<<1)+1];
    p[0] = f2bf(a*sc*w0);
    p[1] = f2bf(c*sc*w1);
    return;
  }
  bid -= 4096;
  __shared__ u16 tile[32][33];
  const int tx = tid & 31, ty = tid >> 5;
  const int s0 = (bid & 63) << 5;
  const int d0 = ((bid >> 6) & 3) << 5;
  const int bk = bid >> 8; const int b = bk >> 2, kv = bk & 3;
  const u16* src = qkv + (size_t)b*2048*3072 + 2560 + kv*128;
  #pragma unroll
  for (int i=0;i<4;i++)
    tile[ty + (i<<3)][tx] = src[(size_t)(s0 + ty + (i<<3))*3072 + d0 + tx];
  __syncthreads();
  u16* dst = vT + (size_t)((b<<2)+kv)*128*2048;
  #pragma unroll
  for (int i=0;i<4;i++)
    dst[(size_t)(d0 + ty + (i<<3))*2048 + s0 + tx] = tile[tx][ty + (i<<3)];
}

// ---------------- 8-phase 256x192 bf16 GEMM for QKV (R15, full 256-block fill) ----------
__global__ __launch_bounds__(512, 2) void gemm192(const u16* __restrict__ A,
    const u16* __restrict__ BT, u16* __restrict__ Cp,
    int M, int N, int K, int ldc)
{
  constexpr int ASZ  = 128*64;         // u16 per A half
  constexpr int BSZ  = 64*64;          // u16 per B slot
  constexpr int DBUF = 2*ASZ + 3*BSZ;  // 28672 u16 = 56 KB
  __shared__ u16 lds[2*DBUF];
  const int tid = threadIdx.x;
  const int w = tid >> 6, lane = tid & 63;
  const int l15 = lane & 15, lg = lane >> 4;
  const int wm = w >> 2, wn = w & 3;
  const int nbx = N / 192;             // 16
  const int nwg = gridDim.x;
  int bid = blockIdx.x;
  bid = (bid & 7) * (nwg >> 3) + (bid >> 3);   // bijective XCD swizzle (nwg%8==0)
  const int m0 = (bid / nbx) << 8;
  const int n0 = (bid % nbx) * 192;

  const u16* gA0 = A  + (size_t)m0*K;
  const u16* gA1 = gA0 + (size_t)128*K;
  const u16* gB  = BT + (size_t)n0*K;

  auto slotA = [&](int d, int h)->u16*{ return lds + d*DBUF + h*ASZ; };
  auto slotB = [&](int d, int s)->u16*{ return lds + d*DBUF + 2*ASZ + s*BSZ; };

  auto stage128 = [&](const u16* gbase, int kt, u16* sbase){
    #pragma unroll
    for (int i=0;i<2;i++){
      const int p = (i<<9) + tid;
      const int row = p>>3, sg = (p&7) ^ (row&7);
      gl_lds16(gbase + (size_t)row*K + (kt<<6) + (sg<<3), sbase + (p<<3));
    }
  };
  auto stage64 = [&](const u16* gbase, int kt, u16* sbase){
    const int row = tid>>3, sg = (tid&7) ^ (row&7);
    gl_lds16(gbase + (size_t)row*K + (kt<<6) + (sg<<3), sbase + (tid<<3));
  };
  auto stA = [&](int kt, int d){ stage128(gA0, kt, slotA(d,0));
                                 stage128(gA1, kt, slotA(d,1)); };
  auto stB = [&](int kt, int d){ stage64(gB,               kt, slotB(d,0));
                                 stage64(gB + (size_t) 64*K, kt, slotB(d,1));
                                 stage64(gB + (size_t)128*K, kt, slotB(d,2)); };
  auto frag_at = [&](const u16* buf, int lrow, int kk)->short8{
    const int s = ((kk<<2)+lg) ^ (lrow&7);
    return *(const short8*)(buf + (((lrow<<3)+s)<<3));
  };

  short8 af[4][2], bfe[2][2], bfo[2];
  f32x4 acc[8][3];
  #pragma unroll
  for (int m=0;m<8;m++)
    #pragma unroll
    for (int n=0;n<3;n++) acc[m][n] = (f32x4){0.f,0.f,0.f,0.f};

  auto rd_a = [&](int d, int mq){
    #pragma unroll
    for (int m=0;m<4;m++)
      #pragma unroll
      for (int kk=0;kk<2;kk++)
        af[m][kk] = frag_at(slotA(d,wm), (mq<<6) + (m<<4) + l15, kk);
  };
  auto rd_be = [&](int d){                   // n-frags 0,1
    #pragma unroll
    for (int n=0;n<2;n++){
      const int r = wn*48 + (n<<4) + l15;
      #pragma unroll
      for (int kk=0;kk<2;kk++)
        bfe[n][kk] = frag_at(slotB(d, r>>6), r&63, kk);
    }
  };
  auto rd_bo = [&](int d){                   // n-frag 2
    const int r = wn*48 + 32 + l15;
    #pragma unroll
    for (int kk=0;kk<2;kk++)
      bfo[kk] = frag_at(slotB(d, r>>6), r&63, kk);
  };
  auto mf_e = [&](int mb){
    __builtin_amdgcn_s_setprio(1);
    #pragma unroll
    for (int m=0;m<4;m++)
      #pragma unroll
      for (int n=0;n<2;n++)
        #pragma unroll
        for (int kk=0;kk<2;kk++)
          acc[mb+m][n] = mfma16(af[m][kk], bfe[n][kk], acc[mb+m][n]);
    __builtin_amdgcn_s_setprio(0);
  };
  auto mf_o = [&](int mb){
    __builtin_amdgcn_s_setprio(1);
    #pragma unroll
    for (int m=0;m<4;m++)
      #pragma unroll
      for (int kk=0;kk<2;kk++)
        acc[mb+m][2] = mfma16(af[m][kk], bfo[kk], acc[mb+m][2]);
    __builtin_amdgcn_s_setprio(0);
  };

  stA(0,0); stB(0,0); stA(1,1);
  waitvm<4>();
  phase_sep();

  const int niter = K >> 7;            // two K-tiles (BK=64) per iteration
  for (int i=0; i<niter; ++i){
    const bool full = (i+1 < niter);
    const int t1 = 2*i+1;
    rd_a(0, 0); rd_be(0);
    stB(t1, 1);
    phase_sep();
    mf_e(0);
    phase_sep();
    rd_bo(0);
    phase_sep();
    mf_o(0);
    phase_sep();
    rd_a(0, 1);
    phase_sep();
    mf_o(4);
    phase_sep();
    rd_be(0);
    if (full) stA(t1+1, 0);
    phase_sep();
    mf_e(4);
    if (full) waitvm<4>(); else waitvm<0>();
    phase_sep();
    rd_a(1, 0); rd_be(1);
    if (full) stB(t1+1, 0);
    phase_sep();
    mf_e(0);
    phase_sep();
    rd_bo(1);
    phase_sep();
    mf_o(0);
    phase_sep();
    rd_a(1, 1);
    phase_sep();
    mf_o(4);
    phase_sep();
    rd_be(1);
    if (full) stA(t1+2, 1);
    phase_sep();
    mf_e(4);
    if (full) waitvm<4>();
    phase_sep();
  }

  #pragma unroll
  for (int m=0;m<8;m++){
    #pragma unroll
    for (int n=0;n<3;n++){
      const int col = n0 + wn*48 + (n<<4) + l15;
      #pragma unroll
      for (int r=0;r<4;r++){
        const int row = m0 + (wm<<7) + (m<<4) + (lg<<2) + r;
        Cp[(size_t)row*ldc + col] = f2bf(acc[m][n][r]);
      }
    }
  }
}

// ---------------- 8-phase BMx256 bf16 GEMM (out-proj; unchanged) ----------------
template<int BM, int CBF16>
__global__ __launch_bounds__(512, 2) void gemm8(const u16* __restrict__ A,
    const u16* __restrict__ BT, void* __restrict__ Cp,
    int M, int N, int K, int ldc)
{
  constexpr int MF   = BM/32;          // M-frags per wave
  constexpr int MQ   = MF/2;           // frags per quadrant phase
  constexpr int AH   = BM/2;           // rows per A half-slot
  constexpr int ASZ  = AH*64;          // u16 per A half-slot
  constexpr int DBUF = 2*ASZ + 16384;  // u16 per dbuf
  constexpr int WV   = (BM==256) ? 4 : 2;  // steady-state vmcnt
  __shared__ u16 lds[2*DBUF];
  const int tid = threadIdx.x;
  const int w = tid >> 6, lane = tid & 63;
  const int l15 = lane & 15, lg = lane >> 4;
  const int wm = w >> 2, wn = w & 3;
  const int nbx = N >> 8;
  const int nwg = gridDim.x;
  int bid = blockIdx.x;
  bid = (bid & 7) * (nwg >> 3) + (bid >> 3);   // bijective XCD swizzle (nwg%8==0)
  const int m0 = (bid / nbx) * BM;
  const int n0 = (bid % nbx) << 8;

  const u16* gA0 = A  + (size_t)m0*K;
  const u16* gA1 = gA0 + (size_t)AH*K;
  const u16* gB0 = BT + (size_t)n0*K;
  const u16* gB1 = gB0 + (size_t)128*K;

  auto slotA = [&](int d, int h)->u16*{ return lds + d*DBUF + h*ASZ; };
  auto slotB = [&](int d, int h)->u16*{ return lds + d*DBUF + 2*ASZ + h*8192; };

  auto stage_half = [&](const u16* gbase, int kt, u16* sbase, int rows){
    const int iters = rows >> 6;               // rows*8/512
    for (int i=0;i<iters;i++){
      const int p = (i<<9) + tid;
      const int row = p>>3, sg = (p&7) ^ (row&7);
      gl_lds16(gbase + (size_t)row*K + (kt<<6) + (sg<<3), sbase + (p<<3));
    }
  };
  auto stA = [&](int kt, int d){ stage_half(gA0, kt, slotA(d,0), AH);
                                 stage_half(gA1, kt, slotA(d,1), AH); };
  auto stB = [&](int kt, int d){ stage_half(gB0, kt, slotB(d,0), 128);
                                 stage_half(gB1, kt, slotB(d,1), 128); };
  auto frag_at = [&](const u16* buf, int lrow, int kk)->short8{
    const int s = ((kk<<2)+lg) ^ (lrow&7);
    return *(const short8*)(buf + (((lrow<<3)+s)<<3));
  };

  short8 af[MQ][2], bfe[2][2], bfo[2][2];
  f32x4 acc[MF][4];
  #pragma unroll
  for (int m=0;m<MF;m++)
    #pragma unroll
    for (int n=0;n<4;n++) acc[m][n] = (f32x4){0.f,0.f,0.f,0.f};

  const int bh = wn>>1;                // my B-half index
  const int brow0 = ((wn&1)<<6) + l15; // base local row in B slot

  auto rd_a = [&](const u16* buf, int mq){
    #pragma unroll
    for (int m=0;m<MQ;m++)
      #pragma unroll
      for (int kk=0;kk<2;kk++)
        af[m][kk] = frag_at(buf, mq*(BM>>2) + (m<<4) + l15, kk);
  };
  auto rd_b = [&](const u16* buf, int nq, short8 (*dst)[2]){
    #pragma unroll
    for (int n=0;n<2;n++)
      #pragma unroll
      for (int kk=0;kk<2;kk++)
        dst[n][kk] = frag_at(buf, brow0 + (nq<<5) + (n<<4), kk);
  };
  auto do_mfma = [&](int mb, int nb, short8 (*bf)[2]){
    __builtin_amdgcn_s_setprio(1);
    #pragma unroll
    for (int m=0;m<MQ;m++)
      #pragma unroll
      for (int n=0;n<2;n++)
        #pragma unroll
        for (int kk=0;kk<2;kk++)
          acc[mb+m][nb+n] = mfma16(af[m][kk], bf[n][kk], acc[mb+m][nb+n]);
    __builtin_amdgcn_s_setprio(0);
  };

  stA(0,0); stB(0,0); stA(1,1);
  waitvm<WV>();
  phase_sep();

  const int niter = K >> 7;            // two K-tiles (BK=64) per iteration
  for (int i=0; i<niter; ++i){
    const bool full = (i+1 < niter);
    const int t1 = 2*i+1;
    rd_a(slotA(0,wm), 0); rd_b(slotB(0,bh), 0, bfe);
    stB(t1, 1);
    phase_sep();
    do_mfma(0, 0, bfe);
    phase_sep();
    rd_b(slotB(0,bh), 1, bfo);
    phase_sep();
    do_mfma(0, 2, bfo);
    phase_sep();
    rd_a(slotA(0,wm), 1);
    phase_sep();
    do_mfma(MQ, 2, bfo);
    phase_sep();
    rd_b(slotB(0,bh), 0, bfe);
    if (full) stA(t1+1, 0);
    phase_sep();
    do_mfma(MQ, 0, bfe);
    if (full) waitvm<WV>(); else waitvm<0>();
    phase_sep();
    rd_a(slotA(1,wm), 0); rd_b(slotB(1,bh), 0, bfe);
    if (full) stB(t1+1, 0);
    phase_sep();
    do_mfma(0, 0, bfe);
    phase_sep();
    rd_b(slotB(1,bh), 1, bfo);
    phase_sep();
    do_mfma(0, 2, bfo);
    phase_sep();
    rd_a(slotA(1,wm), 1);
    phase_sep();
    do_mfma(MQ, 2, bfo);
    phase_sep();
    rd_b(slotB(1,bh), 0, bfe);
    if (full) stA(t1+2, 1);
    phase_sep();
    do_mfma(MQ, 0, bfe);
    if (full) waitvm<WV>();
    phase_sep();
  }

  #pragma unroll
  for (int m=0;m<MF;m++){
    #pragma unroll
    for (int n=0;n<4;n++){
      const int col = n0 + (wn<<6) + (n<<4) + l15;
      #pragma unroll
      for (int r=0;r<4;r++){
        const int row = m0 + wm*AH + (m<<4) + (lg<<2) + r;
        if (CBF16) ((u16*)Cp)[(size_t)row*ldc + col] = f2bf(acc[m][n][r]);
        else       ((float*)Cp)[(size_t)row*ldc + col] = acc[m][n][r];
      }
    }
  }
}

// ---------------- causal GQA flash attention (R16, known-good 64.8 us) ----------
__global__ __launch_bounds__(256, 2) void attn_kernel(const u16* __restrict__ qkv,
    const u16* __restrict__ vT, const float* __restrict__ qw,
    u16* __restrict__ aout)
{
  __shared__ u16 Klds[2][8192];   // [row 64][slot 16] 16B units, slot = d0 ^ (row&15)
  __shared__ u16 Vlds[8192];      // [rp=d/2][sl 16], sl = ((d&1)<<3 | k8) ^ (rp&15)
  const int tid = threadIdx.x;
  const int w = tid >> 6, lane = tid & 63;
  const int l31 = lane & 31, hi = lane >> 5;
  const int bx = blockIdx.x, h = blockIdx.y, b = blockIdx.z;
  const int qI = b ? bx : (15 - bx);
  const int kvh = h >> 2;
  const int qb = qI*128 + (w<<5);            // wave q-base (32 rows)
  const int nt = 2*qI + 2;

  const u16* qkvb = qkv + (size_t)b*2048*3072;
  short8 qf[8];
  {
    const u16* qp = qkvb + (size_t)(qb + l31)*3072 + h*128 + hi*8;
    #pragma unroll
    for (int kk=0;kk<8;kk++) qf[kk] = *(const short8*)(qp + kk*16);
    // ---- fused Q-RMSNorm: row = qb+l31 split across lane and lane^32
    float ss = 0.f;
    #pragma unroll
    for (int kk=0;kk<8;kk++)
      #pragma unroll
      for (int e=0;e<8;e++){
        const float v = bf2f((u16)qf[kk][e]);
        ss += v*v;
      }
    ss += __shfl_xor(ss, 32);
    const float sc = rsqrtf(ss*(1.0f/128.0f) + 1e-6f) * 0.1275187952317199f;
    #pragma unroll
    for (int kk=0;kk<8;kk++){
      #pragma unroll
      for (int e=0;e<8;e++){
        const float wv_ = qw[kk*16 + hi*8 + e];
        qf[kk][e] = (short)f2bf(bf2f((u16)qf[kk][e]) * sc * wv_);
      }
    }
  }
  f32x16 oacc[4];
  #pragma unroll
  for (int d=0;d<4;d++)
    #pragma unroll
    for (int r=0;r<16;r++) oacc[d][r] = 0.f;
  float m_run = -__builtin_inff(), lsum = 0.f;

  const u16* kb_ = qkvb + 2048 + kvh*128;
  const u16* vb_ = vT + (size_t)((b<<2)+kvh)*128*2048;

  auto stageK = [&](int t, int buf){
    #pragma unroll
    for (int i=0;i<4;i++){
      const int u = (i<<8) + tid;            // 0..1023
      const int row = u>>4, d0 = (u&15) ^ (row&15);
      gl_lds16(kb_ + (size_t)((t<<6)+row)*3072 + (d0<<3), &Klds[buf][u<<3]);
    }
  };
  auto stageV = [&](int t){
    #pragma unroll
    for (int i=0;i<4;i++){
      const int u = (i<<8) + tid;
      const int rp = u>>4, z = (u&15) ^ (rp&15);
      const int d = (rp<<1) + (z>>3), k8 = z&7;
      gl_lds16(vb_ + (size_t)d*2048 + (t<<6) + (k8<<3), &Vlds[u<<3]);
    }
  };

  stageK(0, 0);
  int kbuf = 0;
  for (int t=0; t<nt; ++t){
    const bool pre = (t+1 < nt);
    stageV(t);
    if (pre) stageK(t+1, kbuf^1);
    if (pre) waitvm<8>(); else waitvm<4>();  // K(t) landed, prefetches in flight
    phase_sep();
    const int t0 = t<<6;
    // ---- S^T = K Q : lane holds 32 scores for q-row qb + l31
    f32x16 s0, s1;
    #pragma unroll
    for (int r=0;r<16;r++){ s0[r] = 0.f; s1[r] = 0.f; }
    __builtin_amdgcn_s_setprio(1);
    #pragma unroll
    for (int kk=0;kk<8;kk++){
      const int d0 = (kk<<1) + hi;
      const short8 k0 = *(const short8*)&Klds[kbuf][((l31<<4) + (d0 ^ (l31&15)))<<3];
      s0 = mfma32(k0, qf[kk], s0);
      const int r1 = 32 + l31;
      const short8 k1 = *(const short8*)&Klds[kbuf][((r1<<4) + (d0 ^ (r1&15)))<<3];
      s1 = mfma32(k1, qf[kk], s1);
    }
    __builtin_amdgcn_s_setprio(0);
    // ---- causal mask (k-local = (r&3)+8*(r>>2)+4*hi [+32])
    if (t0 + 63 > qb){
      const int qrel = qb + l31 - t0;
      #pragma unroll
      for (int r=0;r<16;r++){
        const int kloc = (r&3) + ((r>>2)<<3) + (hi<<2);
        if (kloc      > qrel) s0[r] = -__builtin_inff();
        if (kloc + 32 > qrel) s1[r] = -__builtin_inff();
      }
    }
    // ---- online softmax (defer-max, exp2 domain)
    float t8[8];
    #pragma unroll
    for (int i=0;i<8;i++) t8[i] = fmaxf(fmaxf(s0[i], s0[i+8]), fmaxf(s1[i], s1[i+8]));
    #pragma unroll
    for (int i=0;i<4;i++) t8[i] = fmaxf(t8[i], t8[i+4]);
    float mx = fmaxf(fmaxf(t8[0],t8[1]), fmaxf(t8[2],t8[3]));
    mx = fmaxf(mx, __shfl_xor(mx, 32));
    const bool noskip = !__all(mx - m_run <= 8.0f);
    const float mnew = noskip ? fmaxf(m_run, mx) : m_run;
    float rs = 0.f;
    #pragma unroll
    for (int i=0;i<16;i++){
      s0[i] = __builtin_amdgcn_exp2f(s0[i] - mnew);
      s1[i] = __builtin_amdgcn_exp2f(s1[i] - mnew);
      rs += s0[i] + s1[i];
    }
    rs += __shfl_xor(rs, 32);
    if (noskip){
      const float corr = __builtin_amdgcn_exp2f(m_run - mnew);
      m_run = mnew;
      lsum = lsum*corr + rs;
      #pragma unroll
      for (int r=0;r<16;r++){
        const float cr = __shfl(corr, (r&3) + ((r>>2)<<3) + (hi<<2));
        #pragma unroll
        for (int db=0;db<4;db++) oacc[db][r] *= cr;
      }
    } else {
      lsum += rs;
    }
    // ---- T12: PV A-frags in-register via cvt_pk + permlane32_swap
    uint32_t paw[4][4];
    #pragma unroll
    for (int kk=0;kk<4;kk++){
      const int base = (kk&1)<<3;
      float v0,v1,v2,v3,v4,v5,v6,v7;
      if (kk<2){ v0=s0[base+0]; v1=s0[base+1]; v2=s0[base+2]; v3=s0[base+3];
                 v4=s0[base+4]; v5=s0[base+5]; v6=s0[base+6]; v7=s0[base+7]; }
      else     { v0=s1[base+0]; v1=s1[base+1]; v2=s1[base+2]; v3=s1[base+3];
                 v4=s1[base+4]; v5=s1[base+5]; v6=s1[base+6]; v7=s1[base+7]; }
      uint32_t a0 = cvtpk(v0, v1), a1 = cvtpk(v2, v3);
      uint32_t b0 = cvtpk(v4, v5), b1 = cvtpk(v6, v7);
      asm volatile("v_permlane32_swap_b32 %0, %1" : "+v"(a0), "+v"(b0));
      asm volatile("v_permlane32_swap_b32 %0, %1" : "+v"(a1), "+v"(b1));
      paw[kk][0] = a0; paw[kk][1] = a1; paw[kk][2] = b0; paw[kk][3] = b1;
    }
    if (pre) waitvm<4>(); else waitvm<0>();  // V(t) landed, K(t+1) in flight
    phase_sep();
    // ---- O += P V
    __builtin_amdgcn_s_setprio(1);
    #pragma unroll
    for (int kk=0;kk<4;kk++){
      union { uint32_t w[4]; short8 v; } pu;
      pu.w[0]=paw[kk][0]; pu.w[1]=paw[kk][1]; pu.w[2]=paw[kk][2]; pu.w[3]=paw[kk][3];
      const short8 pa = pu.v;
      #pragma unroll
      for (int db=0;db<4;db++){
        const int d = (db<<5) + l31, rp = d>>1;
        const int sl = (((d&1)<<3) | ((kk<<1)+hi)) ^ (rp&15);
        const short8 vv = *(const short8*)&Vlds[((rp<<4)+sl)<<3];
        oacc[db] = mfma32(pa, vv, oacc[db]);
      }
    }
    __builtin_amdgcn_s_setprio(0);
    phase_sep();                             // PV reads done before next stageV
    kbuf ^= 1;
  }

  // ---- epilogue: normalize rows, store
  const float inv = 1.0f / lsum;
  #pragma unroll
  for (int r=0;r<16;r++){
    const int qr = (r&3) + ((r>>2)<<3) + (hi<<2);
    const float ivr = __shfl(inv, qr);
    u16* op = aout + (size_t)(b*2048 + qb + qr)*2048 + h*128 + l31;
    #pragma unroll
    for (int db=0;db<4;db++)
      op[db<<5] = f2bf(oacc[db][r] * ivr);
  }
}

extern "C" void kernel_launch(void* const* d_in, const int* in_sizes, int n_in,
                              void* d_out, int out_size, void* d_ws, size_t ws_size,
                              hipStream_t stream) {
  const float* x  = (const float*)d_in[0];
  const float* wq = (const float*)d_in[1];
  const float* wk = (const float*)d_in[2];
  const float* wv = (const float*)d_in[3];
  const float* wo = (const float*)d_in[4];
  const float* qw = (const float*)d_in[5];
  const float* kw = (const float*)d_in[6];
  char* ws = (char*)d_ws;
  u16* xbf   = (u16*)(ws);                 // 16 MB; reused as attn_out
  u16* wqkvT = (u16*)(ws + 16777216);      // 12 MB: [3072][2048] = wqT|wkT|wvT
  u16* woT   = (u16*)(ws + 29360128);      // 8 MB:  [2048][2048]
  u16* qkv   = (u16*)(ws + 37748736);      // 24 MB: [4096][3072] q|k|v
  u16* vT    = (u16*)(ws + 62914560);      // 4 MB:  [8][128][2048]
  float* out = (float*)d_out;

  prep<<<18432, 256, 0, stream>>>(x, wq, wk, wv, wo, xbf, wqkvT, woT);
  gemm192<<<256, 512, 0, stream>>>(xbf, wqkvT, qkv, 4096, 3072, 2048, 3072);
  norm_vt<<<6144, 256, 0, stream>>>(qkv, kw, vT);
  attn_kernel<<<dim3(16,16,2), 256, 0, stream>>>(qkv, vT, qw, xbf);
  gemm8<128,0><<<256, 512, 0, stream>>>(xbf, woT, out, 4096, 2048, 2048, 2048);
}